// Round 1
// baseline (170.914 us; speedup 1.0000x reference)
//
#include <hip/hip_runtime.h>
#include <math.h>

#define NTHREADS 256

// 16 node weight pointers.
struct PW {
    const float* w[16];
    int perp[16];
};

// ---------------------------------------------------------------------------
// Gram precompute: per node n, G00=<w0,w0>, G01=<w0,w1>, G11=<w1,w1> -> d_ws.
// ---------------------------------------------------------------------------
__global__ __launch_bounds__(NTHREADS) void gram16(PW pw, float* __restrict__ g) {
    const int n = blockIdx.x;
    const float* __restrict__ W = pw.w[n];
    const int m = pw.perp[n];
    float s00 = 0.f, s01 = 0.f, s11 = 0.f;
    for (int e = threadIdx.x; e < m; e += NTHREADS) {
        float a = W[e], b = W[m + e];
        s00 += a * a; s01 += a * b; s11 += b * b;
    }
    for (int off = 32; off > 0; off >>= 1) {
        s00 += __shfl_down(s00, off, 64);
        s01 += __shfl_down(s01, off, 64);
        s11 += __shfl_down(s11, off, 64);
    }
    __shared__ float red[4][3];
    const int lane = threadIdx.x & 63, wv = threadIdx.x >> 6;
    if (lane == 0) { red[wv][0] = s00; red[wv][1] = s01; red[wv][2] = s11; }
    __syncthreads();
    if (threadIdx.x == 0) {
        float t0 = 0.f, t1 = 0.f, t2 = 0.f;
        for (int i = 0; i < 4; i++) { t0 += red[i][0]; t1 += red[i][1]; t2 += red[i][2]; }
        g[n * 3 + 0] = t0; g[n * 3 + 1] = t1; g[n * 3 + 2] = t2;
    }
}

// ---------------------------------------------------------------------------
// LDS arena layout per sample (floats). 2 samples per block.
// Big slots A..D (1296), small T slots X,Y,Z (216), tiny U,V (36), pipe P (216).
// ---------------------------------------------------------------------------
constexpr int SA = 0, SB = 1296, SC = 2592, SD = 3888;
constexpr int SP = 5184, SX = 5400, SY = 5616, SZ = 5832, SU = 6048, SV = 6084;
constexpr int ARENA = 6120;   // floats per sample; 2*ARENA*4 = 48960 B -> 3 blocks/CU

// ---------------------------------------------------------------------------
// Staging: t = al*w0 + be*w1, identity layout (vectorized float2).
// ---------------------------------------------------------------------------
template<int TOT, int DST>
__device__ __forceinline__ void stg_id(float* __restrict__ lds, const float* __restrict__ W,
                                       float a0, float b0, float a1, float b1, int tid) {
    constexpr int PAIRS = TOT / 2;
    for (int e = tid; e < 2 * PAIRS; e += NTHREADS) {
        const int s = (e >= PAIRS);
        const int p = e - s * PAIRS;
        const float al = s ? a1 : a0, be = s ? b1 : b0;
        const float2 u0 = *reinterpret_cast<const float2*>(W + 2 * p);
        const float2 u1 = *reinterpret_cast<const float2*>(W + TOT + 2 * p);
        float2 rv; rv.x = al * u0.x + be * u1.x; rv.y = al * u0.y + be * u1.y;
        *reinterpret_cast<float2*>(lds + s * ARENA + DST + 2 * p) = rv;
    }
}

// Staging with permutation: dest dims (D0 outer .. D3 inner), src strides S0..S3
// for those same axes.
template<int D0, int D1, int D2, int D3, int S0, int S1, int S2, int S3, int DST>
__device__ __forceinline__ void stg_pm(float* __restrict__ lds, const float* __restrict__ W,
                                       float a0, float b0, float a1, float b1, int tid) {
    constexpr int TOT = D0 * D1 * D2 * D3;
    for (int e = tid; e < 2 * TOT; e += NTHREADS) {
        const int s = (e >= TOT);
        const int d = e - s * TOT;
        int r = d;
        const int i3 = r % D3; r /= D3;
        const int i2 = r % D2; r /= D2;
        const int i1 = r % D1;
        const int i0 = r / D1;
        const int src = i0 * S0 + i1 * S1 + i2 * S2 + i3 * S3;
        const float al = s ? a1 : a0, be = s ? b1 : b0;
        lds[s * ARENA + DST + d] = al * W[src] + be * W[TOT + src];
    }
}

// ---------------------------------------------------------------------------
// Matmul step over BOTH samples: out[m,n] = sum_k A[k][m] * B[k][n].
// A dense [K][M] (m contiguous), B dense [K][N] (n contiguous); 6x6 register
// tile per thread, float2 LDS loads. Output written with per-axis strides:
// m = m1*NM2 + m2 (NM2>=M means single axis), idx = m1*OSM1+m2*OSM2+n1*OSN1+n2*OSN2.
// ---------------------------------------------------------------------------
template<int M, int N, int K,
         int NM2, int OSM1, int OSM2,
         int NN2, int OSN1, int OSN2,
         int AOFF, int BOFF, int OOFF>
__device__ __forceinline__ void mm(float* __restrict__ lds, int tid) {
    constexpr int TM = 6, TN = 6;
    constexpr int WN = N / TN;
    constexpr int PER_S = (M / TM) * WN;
    constexpr int TOT = 2 * PER_S;
    for (int w = tid; w < TOT; w += NTHREADS) {
        const int s = (w >= PER_S);
        const int r = w - s * PER_S;
        const int mt = r / WN;
        const int nt = r - mt * WN;
        const float* __restrict__ Ab = lds + s * ARENA + AOFF + mt * TM;
        const float* __restrict__ Bb = lds + s * ARENA + BOFF + nt * TN;
        float acc[TM][TN];
#pragma unroll
        for (int i = 0; i < TM; i++)
#pragma unroll
            for (int j = 0; j < TN; j++) acc[i][j] = 0.f;
#pragma unroll 6
        for (int k = 0; k < K; ++k) {
            float a[TM], b[TN];
            const float2* __restrict__ Ap = reinterpret_cast<const float2*>(Ab + k * M);
            const float2* __restrict__ Bp = reinterpret_cast<const float2*>(Bb + k * N);
#pragma unroll
            for (int i = 0; i < TM / 2; i++) { const float2 v = Ap[i]; a[2 * i] = v.x; a[2 * i + 1] = v.y; }
#pragma unroll
            for (int j = 0; j < TN / 2; j++) { const float2 v = Bp[j]; b[2 * j] = v.x; b[2 * j + 1] = v.y; }
#pragma unroll
            for (int i = 0; i < TM; i++)
#pragma unroll
                for (int j = 0; j < TN; j++) acc[i][j] += a[i] * b[j];
        }
        float* __restrict__ Ob = lds + s * ARENA + OOFF;
#pragma unroll
        for (int i = 0; i < TM; i++) {
            int m1, m2;
            if constexpr (NM2 >= M) { m1 = 0; m2 = mt * TM + i; }
            else                    { m1 = mt; m2 = i; }   // requires TM == NM2 (6)
#pragma unroll
            for (int j = 0; j < TN; j++) {
                int n1, n2;
                if constexpr (NN2 >= N) { n1 = 0; n2 = nt * TN + j; }
                else                    { n1 = nt; n2 = j; }
                Ob[m1 * OSM1 + m2 * OSM2 + n1 * OSN1 + n2 * OSN2] = acc[i][j];
            }
        }
    }
}

// ---------------------------------------------------------------------------
// Main: one block = 2 samples. Same contraction DAG as before; every step is a
// [K][M]x[K][N] matmul; producers write exactly the layout consumers need.
// ---------------------------------------------------------------------------
__global__ __launch_bounds__(NTHREADS, 4) void peps_main(const float* __restrict__ x, PW pw,
                                                         const float* __restrict__ gram,
                                                         float* __restrict__ out) {
    __shared__ float lds[2 * ARENA];
    __shared__ float cfa[2][16], cfb[2][16];
    __shared__ float red[4][2][10];

    const int tid = threadIdx.x;
    const int s0 = blockIdx.x * 2;

    // per-node normalized coefficients for both samples
    if (tid < 32) {
        const int sl = tid >> 4, n = tid & 15;
        const float a = x[(s0 + sl) * 32 + n * 2 + 0];
        const float b = x[(s0 + sl) * 32 + n * 2 + 1];
        const float g0 = gram[n * 3 + 0], g1 = gram[n * 3 + 1], g2 = gram[n * 3 + 2];
        const float inv = 1.f / sqrtf(a * a * g0 + 2.f * a * b * g1 + b * b * g2);
        cfa[sl][n] = a * inv; cfb[sl][n] = b * inv;
    }
    __syncthreads();

#define CF(WI) cfa[0][WI], cfb[0][WI], cfa[1][WI], cfb[1][WI]

    // P0: stage t00->U [h00][v00], t01->X [h00][v01,h01], t10->Y [v00][v10,h10], t11->A [v01,h10][v11,h11]
    stg_pm<1, 1, 6, 6, 0, 0, 1, 6, SU>(lds, pw.w[0], CF(0), tid);
    stg_id<216, SX>(lds, pw.w[1], CF(1), tid);
    stg_id<216, SY>(lds, pw.w[4], CF(4), tid);
    stg_id<1296, SA>(lds, pw.w[5], CF(5), tid);
    __syncthreads();

    // P1: S1 TL1[v00][(v01,h01)] = t00^T x t01 -> P ; stage t02->Z [h02][h01,v02], t03->V [h02][v03]
    mm<6, 36, 6, 6, 0, 36, 36, 0, 1, SU, SX, SP>(lds, tid);
    stg_pm<1, 6, 6, 6, 0, 1, 36, 6, SZ>(lds, pw.w[2], CF(2), tid);
    stg_id<36, SV>(lds, pw.w[3], CF(3), tid);
    __syncthreads();

    // P2: S2 TL2 -> B as [v01][h10][h01][v10] ; stage t13->X [v03][h12,v13], t30->U [v20][h30]
    mm<36, 36, 6, 6, 216, 6, 6, 1, 36, SP, SY, SB>(lds, tid);
    stg_id<216, SX>(lds, pw.w[7], CF(7), tid);
    stg_id<36, SU>(lds, pw.w[12], CF(12), tid);
    __syncthreads();

    // P3: S3 TL = TL2(B) x t11(A) -> C [h01][h11][v10][v11]
    //     S4 TR1 = t02(Z) x t03(V) -> P [v03][(h01,v02)] ; stage t20->Y [v20][v10,h20]
    mm<36, 36, 36, 6, 216, 6, 6, 1, 36, SB, SA, SC>(lds, tid);
    mm<36, 6, 6, 36, 0, 1, 6, 0, 36, SZ, SV, SP>(lds, tid);
    stg_pm<1, 6, 6, 6, 0, 6, 36, 1, SY>(lds, pw.w[8], CF(8), tid);
    __syncthreads();

    // P4: S5 TR2 = TR1(P) x t13(X) -> B [v02][h12][h01][v13] ; stage t12->A [v02][h12][h11,v12]
    mm<36, 36, 6, 6, 6, 216, 6, 36, 1, SP, SX, SB>(lds, tid);
    stg_pm<6, 6, 6, 6, 216, 1, 36, 6, SA>(lds, pw.w[6], CF(6), tid);
    __syncthreads();

    // P5: S6 TR' = t12(A) x TR2(B) -> D [h01][h11][v12][v13] ; stage t31->Z [h30][v21,h31]
    mm<36, 36, 36, 6, 36, 6, 6, 216, 1, SA, SB, SD>(lds, tid);
    stg_pm<1, 6, 6, 6, 0, 6, 36, 1, SZ>(lds, pw.w[13], CF(13), tid);
    __syncthreads();

    // P6: S7 TOP = TL(C) x TR'(D) -> A [v10][v11][v12][v13]
    //     S8 BL1 = t30(U) x t20(Y) -> P [h30][(v10,h20)]
    //     stage t21->B [h20][v21][v11,h21], t23->X [v23][v13,h22], t33->V [v23][h32]
    mm<36, 36, 36, 6, 216, 36, 6, 6, 1, SC, SD, SA>(lds, tid);
    mm<6, 36, 6, 6, 0, 36, 36, 0, 1, SU, SY, SP>(lds, tid);
    stg_pm<6, 6, 6, 6, 36, 6, 216, 1, SB>(lds, pw.w[9], CF(9), tid);
    stg_pm<1, 6, 6, 6, 0, 1, 36, 6, SX>(lds, pw.w[11], CF(11), tid);
    stg_id<36, SV>(lds, pw.w[15], CF(15), tid);
    __syncthreads();

    // P7: S9 BL2 = BL1(P) x t31(Z) -> C [h20][v21][v10][h31] ; stage t32->Y [h32][v22,h31]
    mm<36, 36, 6, 6, 6, 216, 6, 36, 1, SP, SZ, SC>(lds, tid);
    stg_pm<1, 6, 6, 6, 0, 1, 36, 6, SY>(lds, pw.w[14], CF(14), tid);
    __syncthreads();

    // P8: S10 BL = BL2(C) x t21(B) -> D [v10][v11][h31][h21]
    //     S12 R1 = t23(X) x t33(V) -> P [h32][(v13,h22)]
    mm<36, 36, 36, 6, 216, 6, 6, 36, 1, SC, SB, SD>(lds, tid);
    mm<36, 6, 6, 36, 0, 1, 6, 0, 36, SX, SV, SP>(lds, tid);
    __syncthreads();

    // P9: S11 M1 = TOP(A) x BL(D) -> C [v13][h31][v12][h21]
    //     S13 R' = R1(P) x t32(Y) -> B [v13][h31][v22][h22]
    mm<36, 36, 36, 6, 6, 216, 6, 36, 1, SA, SD, SC>(lds, tid);
    mm<36, 36, 6, 6, 216, 1, 6, 6, 36, SP, SY, SB>(lds, tid);
    __syncthreads();

    // P10: S14 E = M1(C) x R'(B) -> A [v12][h21][v22][h22] (matches w22 linear order)
    mm<36, 36, 36, 6, 216, 36, 6, 6, 1, SC, SB, SA>(lds, tid);
    __syncthreads();

    // ---- epilogue: out[o] = sum_e E[e]*(a*w22_0[e,o]+b*w22_1[e,o]); normalize ----
    {
        const float a0 = cfa[0][10], b0 = cfb[0][10];
        const float a1 = cfa[1][10], b1 = cfb[1][10];
        const float* __restrict__ w0 = pw.w[10];
        const float* __restrict__ w1 = w0 + 12960;
        float p0[10], p1[10];
#pragma unroll
        for (int o = 0; o < 10; o++) { p0[o] = 0.f; p1[o] = 0.f; }
        for (int e = tid; e < 1296; e += NTHREADS) {
            const float E0 = lds[SA + e];
            const float E1 = lds[ARENA + SA + e];
            const float* __restrict__ q0 = w0 + e * 10;
            const float* __restrict__ q1 = w1 + e * 10;
#pragma unroll
            for (int o = 0; o < 10; o++) {
                const float v0 = q0[o], v1 = q1[o];
                p0[o] += E0 * (a0 * v0 + b0 * v1);
                p1[o] += E1 * (a1 * v0 + b1 * v1);
            }
        }
#pragma unroll
        for (int o = 0; o < 10; o++)
            for (int off = 32; off > 0; off >>= 1) {
                p0[o] += __shfl_down(p0[o], off, 64);
                p1[o] += __shfl_down(p1[o], off, 64);
            }
        const int lane = tid & 63, wv = tid >> 6;
        if (lane == 0) {
#pragma unroll
            for (int o = 0; o < 10; o++) { red[wv][0][o] = p0[o]; red[wv][1][o] = p1[o]; }
        }
        __syncthreads();
        if (tid < 2) {
            float r[10];
            float ss = 0.f;
#pragma unroll
            for (int o = 0; o < 10; o++) {
                r[o] = red[0][tid][o] + red[1][tid][o] + red[2][tid][o] + red[3][tid][o];
                ss += r[o] * r[o];
            }
            const float inv = 1.f / sqrtf(ss);
#pragma unroll
            for (int o = 0; o < 10; o++) out[(s0 + tid) * 10 + o] = r[o] * inv;
        }
    }
#undef CF
}

extern "C" void kernel_launch(void* const* d_in, const int* in_sizes, int n_in,
                              void* d_out, int out_size, void* d_ws, size_t ws_size,
                              hipStream_t stream) {
    PW pw;
    for (int k = 0; k < 16; k++) {
        pw.w[k] = (const float*)d_in[1 + k];
        pw.perp[k] = in_sizes[1 + k] / 2;
    }
    float* gram = (float*)d_ws;             // 16*3 floats
    gram16<<<16, NTHREADS, 0, stream>>>(pw, gram);

    const float* x = (const float*)d_in[0];
    const int B = out_size / 10;            // 2048 samples
    peps_main<<<B / 2, NTHREADS, 0, stream>>>(x, pw, gram, (float*)d_out);
}

// Round 2
// 142.274 us; speedup vs baseline: 1.2013x; 1.2013x over previous
//
#include <hip/hip_runtime.h>
#include <math.h>

#define NTHREADS 256

// 16 node weight pointers.
struct PW {
    const float* w[16];
    int perp[16];
};

// ---------------------------------------------------------------------------
// Gram precompute, 4 partial slices per node (64 blocks -> fills the GPU).
// g[n*12 + slice*3 + {0,1,2}] = partial {<w0,w0>, <w0,w1>, <w1,w1>}.
// ---------------------------------------------------------------------------
__global__ __launch_bounds__(NTHREADS) void gram64(PW pw, float* __restrict__ g) {
    const int n = blockIdx.x >> 2, sl = blockIdx.x & 3;
    const float* __restrict__ W = pw.w[n];
    const int m = pw.perp[n];
    float s00 = 0.f, s01 = 0.f, s11 = 0.f;
    for (int e = sl * NTHREADS + threadIdx.x; e < m; e += 4 * NTHREADS) {
        float a = W[e], b = W[m + e];
        s00 += a * a; s01 += a * b; s11 += b * b;
    }
    for (int off = 32; off > 0; off >>= 1) {
        s00 += __shfl_down(s00, off, 64);
        s01 += __shfl_down(s01, off, 64);
        s11 += __shfl_down(s11, off, 64);
    }
    __shared__ float red[4][3];
    const int lane = threadIdx.x & 63, wv = threadIdx.x >> 6;
    if (lane == 0) { red[wv][0] = s00; red[wv][1] = s01; red[wv][2] = s11; }
    __syncthreads();
    if (threadIdx.x == 0) {
        float t0 = 0.f, t1 = 0.f, t2 = 0.f;
        for (int i = 0; i < 4; i++) { t0 += red[i][0]; t1 += red[i][1]; t2 += red[i][2]; }
        g[n * 12 + sl * 3 + 0] = t0; g[n * 12 + sl * 3 + 1] = t1; g[n * 12 + sl * 3 + 2] = t2;
    }
}

// ---------------------------------------------------------------------------
// LDS arena per sample (floats). 2 samples/block. 3 big slots + 5 small slots.
// Liveness (audited):
//  A: t11(P0-P3) TL(P3-P6) TOP(P6-P9) M1(P9-P10) E(P10-epi)
//  B: TL2(P2-P3) TR2(P4-P5) TR'(P5-P6) BL2(P7-P8) R'(P8-P10)
//  C: t12(P2-P5) t21(P6-P8) BL(P8-P9)
//  P: TL1(P1-P2) TR1(P3-P4) BL1(P5-P7)
//  Q: t00(P0-P1)@+0 t03(P1-P3)@+36 t30(P2-P5)@+72 t33(P5-P7)@+108 R1(P7-P8)full
//  X: t01(P0-P1) t13(P2-P4) t23(P5-P7)
//  Y: t10(P0-P2) t20(P3-P5) t32(P6-P8)
//  Z: t02(P1-P3) t31(P4-P7)
// ---------------------------------------------------------------------------
constexpr int SA = 0, SB = 1296, SC = 2592;
constexpr int SP = 3888, SQ = 4104, SX = 4320, SY = 4536, SZ = 4752;
constexpr int ARENA = 4968;   // 2*ARENA*4 = 39744 B (+static 576 B) -> 4 blocks/CU

// ---------------------------------------------------------------------------
// Staging: t = al*w0 + be*w1, identity layout (vectorized float2).
// ---------------------------------------------------------------------------
template<int TOT, int DST>
__device__ __forceinline__ void stg_id(float* __restrict__ lds, const float* __restrict__ W,
                                       float a0, float b0, float a1, float b1, int tid) {
    constexpr int PAIRS = TOT / 2;
    for (int e = tid; e < 2 * PAIRS; e += NTHREADS) {
        const int s = (e >= PAIRS);
        const int p = e - s * PAIRS;
        const float al = s ? a1 : a0, be = s ? b1 : b0;
        const float2 u0 = *reinterpret_cast<const float2*>(W + 2 * p);
        const float2 u1 = *reinterpret_cast<const float2*>(W + TOT + 2 * p);
        float2 rv; rv.x = al * u0.x + be * u1.x; rv.y = al * u0.y + be * u1.y;
        *reinterpret_cast<float2*>(lds + s * ARENA + DST + 2 * p) = rv;
    }
}

// Staging with permutation: dest dims (D0 outer .. D3 inner), src strides S0..S3.
template<int D0, int D1, int D2, int D3, int S0, int S1, int S2, int S3, int DST>
__device__ __forceinline__ void stg_pm(float* __restrict__ lds, const float* __restrict__ W,
                                       float a0, float b0, float a1, float b1, int tid) {
    constexpr int TOT = D0 * D1 * D2 * D3;
    for (int e = tid; e < 2 * TOT; e += NTHREADS) {
        const int s = (e >= TOT);
        const int d = e - s * TOT;
        int r = d;
        const int i3 = r % D3; r /= D3;
        const int i2 = r % D2; r /= D2;
        const int i1 = r % D1;
        const int i0 = r / D1;
        const int src = i0 * S0 + i1 * S1 + i2 * S2 + i3 * S3;
        const float al = s ? a1 : a0, be = s ? b1 : b0;
        lds[s * ARENA + DST + d] = al * W[src] + be * W[TOT + src];
    }
}

// ---------------------------------------------------------------------------
// Matmul: out[m,n] = sum_k A[k][m] * B[k][n]; A [K][M] m-contig, B [K][N]
// n-contig. Thread tile fixed 2x6 -> up to 216 active threads (all 4 SIMDs).
// Split into acc (compute to regs) / wr (store with per-axis strides) so big
// steps can write IN-PLACE over an input slot after a mid-phase barrier.
// ---------------------------------------------------------------------------
template<int M, int N, int K, int AOFF, int BOFF>
__device__ __forceinline__ void mm_acc(const float* __restrict__ lds, int tid,
                                       float (&acc)[2][6]) {
    constexpr int WM = M / 2, WN = N / 6, PER_S = WM * WN, TOT = 2 * PER_S;
    static_assert(TOT <= NTHREADS, "tile overflow");
    if (tid >= TOT) return;
    const int s = (tid >= PER_S);
    const int r = tid - s * PER_S;
    const int mt = r / WN, nt = r - mt * WN;
    const float* __restrict__ Ab = lds + s * ARENA + AOFF + mt * 2;
    const float* __restrict__ Bb = lds + s * ARENA + BOFF + nt * 6;
#pragma unroll
    for (int i = 0; i < 2; i++)
#pragma unroll
        for (int j = 0; j < 6; j++) acc[i][j] = 0.f;
#pragma unroll 6
    for (int k = 0; k < K; ++k) {
        const float2 av = *reinterpret_cast<const float2*>(Ab + k * M);
        const float2 b0 = *reinterpret_cast<const float2*>(Bb + k * N);
        const float2 b1 = *reinterpret_cast<const float2*>(Bb + k * N + 2);
        const float2 b2 = *reinterpret_cast<const float2*>(Bb + k * N + 4);
        const float aa[2] = {av.x, av.y};
        const float bb[6] = {b0.x, b0.y, b1.x, b1.y, b2.x, b2.y};
#pragma unroll
        for (int i = 0; i < 2; i++)
#pragma unroll
            for (int j = 0; j < 6; j++) acc[i][j] += aa[i] * bb[j];
    }
}

template<int M, int N, int NM2, int OSM1, int OSM2, int NN2, int OSN1, int OSN2, int OOFF>
__device__ __forceinline__ void mm_wr(float* __restrict__ lds, int tid,
                                      const float (&acc)[2][6]) {
    constexpr int WM = M / 2, WN = N / 6, PER_S = WM * WN, TOT = 2 * PER_S;
    if (tid >= TOT) return;
    const int s = (tid >= PER_S);
    const int r = tid - s * PER_S;
    const int mt = r / WN, nt = r - mt * WN;
    float* __restrict__ Ob = lds + s * ARENA + OOFF;
#pragma unroll
    for (int i = 0; i < 2; i++) {
        const int m = mt * 2 + i;
        int m1, m2;
        if constexpr (NM2 >= M) { m1 = 0; m2 = m; }
        else                    { m1 = m / NM2; m2 = m - m1 * NM2; }
#pragma unroll
        for (int j = 0; j < 6; j++) {
            int n1, n2;
            if constexpr (NN2 >= N) { n1 = 0; n2 = nt * 6 + j; }
            else                    { n1 = nt; n2 = j; }   // TN == NN2 == 6
            Ob[m1 * OSM1 + m2 * OSM2 + n1 * OSN1 + n2 * OSN2] = acc[i][j];
        }
    }
}

// Direct (non-deferred) matmul: output slot disjoint from all same-phase-live.
template<int M, int N, int K, int NM2, int OSM1, int OSM2, int NN2, int OSN1, int OSN2,
         int AOFF, int BOFF, int OOFF>
__device__ __forceinline__ void mmd(float* __restrict__ lds, int tid) {
    float acc[2][6];
    mm_acc<M, N, K, AOFF, BOFF>(lds, tid, acc);
    mm_wr<M, N, NM2, OSM1, OSM2, NN2, OSN1, OSN2, OOFF>(lds, tid, acc);
}

// ---------------------------------------------------------------------------
// Main: one block = 2 samples, 4 blocks/CU resident (single dispatch round).
// Layout template args byte-identical to the verified R1 kernel; only slots,
// tiling (2x6) and in-place deferred writes changed.
// ---------------------------------------------------------------------------
__global__ __launch_bounds__(NTHREADS, 4) void peps_main(const float* __restrict__ x, PW pw,
                                                         const float* __restrict__ gram,
                                                         float* __restrict__ out) {
    __shared__ float lds[2 * ARENA];
    __shared__ float cfa[2][16], cfb[2][16];
    __shared__ float red[4][2][10];

    const int tid = threadIdx.x;
    const int s0 = blockIdx.x * 2;

    // per-node normalized coefficients for both samples (sum 4 gram partials)
    if (tid < 32) {
        const int sl = tid >> 4, n = tid & 15;
        const float a = x[(s0 + sl) * 32 + n * 2 + 0];
        const float b = x[(s0 + sl) * 32 + n * 2 + 1];
        float g0 = 0.f, g1 = 0.f, g2 = 0.f;
#pragma unroll
        for (int q = 0; q < 4; q++) {
            g0 += gram[n * 12 + q * 3 + 0];
            g1 += gram[n * 12 + q * 3 + 1];
            g2 += gram[n * 12 + q * 3 + 2];
        }
        const float inv = 1.f / sqrtf(a * a * g0 + 2.f * a * b * g1 + b * b * g2);
        cfa[sl][n] = a * inv; cfb[sl][n] = b * inv;
    }
    __syncthreads();

#define CF(WI) cfa[0][WI], cfb[0][WI], cfa[1][WI], cfb[1][WI]

    // P0: stage t00->Q0 [h00][v00], t01->X, t10->Y, t11->A
    stg_pm<1, 1, 6, 6, 0, 0, 1, 6, SQ + 0>(lds, pw.w[0], CF(0), tid);
    stg_id<216, SX>(lds, pw.w[1], CF(1), tid);
    stg_id<216, SY>(lds, pw.w[4], CF(4), tid);
    stg_id<1296, SA>(lds, pw.w[5], CF(5), tid);
    __syncthreads();

    // P1: S1 TL1[v00][(v01,h01)] = t00(Q0) x t01(X) -> P ; stage t02->Z, t03->Q1
    mmd<6, 36, 6, 6, 0, 36, 36, 0, 1, SQ + 0, SX, SP>(lds, tid);
    stg_pm<1, 6, 6, 6, 0, 1, 36, 6, SZ>(lds, pw.w[2], CF(2), tid);
    stg_id<36, SQ + 36>(lds, pw.w[3], CF(3), tid);
    __syncthreads();

    // P2: S2 TL2[v01][h10][h01][v10] = TL1(P) x t10(Y) -> B
    //     stage t13->X, t12->C [v02][h12][h11][v12], t30->Q2
    mmd<36, 36, 6, 6, 216, 6, 6, 1, 36, SP, SY, SB>(lds, tid);
    stg_id<216, SX>(lds, pw.w[7], CF(7), tid);
    stg_pm<6, 6, 6, 6, 216, 1, 36, 6, SC>(lds, pw.w[6], CF(6), tid);
    stg_id<36, SQ + 72>(lds, pw.w[12], CF(12), tid);
    __syncthreads();

    // P3: S3 TL = TL2(B) x t11(A) [K=36] (defer -> A)
    //     S4 TR1[v03][(h01,v02)] = t02(Z) x t03(Q1) -> P ; stage t20->Y
    {
        float a3[2][6];
        mm_acc<36, 36, 36, SB, SA>(lds, tid, a3);
        mmd<36, 6, 6, 36, 0, 1, 6, 0, 36, SZ, SQ + 36, SP>(lds, tid);
        stg_pm<1, 6, 6, 6, 0, 6, 36, 1, SY>(lds, pw.w[8], CF(8), tid);
        __syncthreads();
        mm_wr<36, 36, 6, 216, 6, 6, 1, 36, SA>(lds, tid, a3);   // TL [h01][h11][v10][v11]
    }
    __syncthreads();

    // P4: S5 TR2[v02][h12][h01][v13] = TR1(P) x t13(X) -> B ; stage t31->Z
    mmd<36, 36, 6, 6, 6, 216, 6, 36, 1, SP, SX, SB>(lds, tid);
    stg_pm<1, 6, 6, 6, 0, 6, 36, 1, SZ>(lds, pw.w[13], CF(13), tid);
    __syncthreads();

    // P5: S6 TR' = t12(C) x TR2(B) [K=36] (defer -> B)
    //     S8 BL1[h30][(v10,h20)] = t30(Q2) x t20(Y) -> P ; stage t33->Q3, t23->X
    {
        float a6[2][6];
        mm_acc<36, 36, 36, SC, SB>(lds, tid, a6);
        mmd<6, 36, 6, 6, 0, 36, 36, 0, 1, SQ + 72, SY, SP>(lds, tid);
        stg_id<36, SQ + 108>(lds, pw.w[15], CF(15), tid);
        stg_pm<1, 6, 6, 6, 0, 1, 36, 6, SX>(lds, pw.w[11], CF(11), tid);
        __syncthreads();
        mm_wr<36, 36, 6, 36, 6, 6, 216, 1, SB>(lds, tid, a6);   // TR' [h01][h11][v12][v13]
    }
    __syncthreads();

    // P6: S7 TOP = TL(A) x TR'(B) [K=36] (defer -> A)
    //     stage t21->C [h20][v21][v11][h21], t32->Y
    {
        float a7[2][6];
        mm_acc<36, 36, 36, SA, SB>(lds, tid, a7);
        stg_pm<6, 6, 6, 6, 36, 6, 216, 1, SC>(lds, pw.w[9], CF(9), tid);
        stg_pm<1, 6, 6, 6, 0, 1, 36, 6, SY>(lds, pw.w[14], CF(14), tid);
        __syncthreads();
        mm_wr<36, 36, 6, 216, 36, 6, 6, 1, SA>(lds, tid, a7);   // TOP [v10][v11][v12][v13]
    }
    __syncthreads();

    // P7: S9 BL2[h20][v21][v10][h31] = BL1(P) x t31(Z) -> B
    //     S12 R1[h32][(v13,h22)] = t23(X) x t33(Q3) (defer -> Q full)
    {
        float a12[2][6];
        mm_acc<36, 6, 6, SX, SQ + 108>(lds, tid, a12);
        mmd<36, 36, 6, 6, 6, 216, 6, 36, 1, SP, SZ, SB>(lds, tid);
        __syncthreads();
        mm_wr<36, 6, 36, 0, 1, 6, 0, 36, SQ>(lds, tid, a12);
    }
    __syncthreads();

    // P8: S10 BL = BL2(B) x t21(C) [K=36] (defer -> C)
    //     S13 R' = R1(Q) x t32(Y) [K=6]  (defer -> B)
    {
        float a10[2][6], a13[2][6];
        mm_acc<36, 36, 36, SB, SC>(lds, tid, a10);
        mm_acc<36, 36, 6, SQ, SY>(lds, tid, a13);
        __syncthreads();
        mm_wr<36, 36, 6, 216, 6, 6, 36, 1, SC>(lds, tid, a10);  // BL [v10][v11][h31][h21]
        mm_wr<36, 36, 6, 216, 1, 6, 6, 36, SB>(lds, tid, a13);  // R' [v13][h31][v22][h22]
    }
    __syncthreads();

    // P9: S11 M1 = TOP(A) x BL(C) [K=36] (defer -> A)
    {
        float a11[2][6];
        mm_acc<36, 36, 36, SA, SC>(lds, tid, a11);
        __syncthreads();
        mm_wr<36, 36, 6, 6, 216, 6, 36, 1, SA>(lds, tid, a11);  // M1 [v13][h31][v12][h21]
    }
    __syncthreads();

    // P10: S14 E = M1(A) x R'(B) [K=36] (defer -> A) ; E [v12][h21][v22][h22]
    {
        float a14[2][6];
        mm_acc<36, 36, 36, SA, SB>(lds, tid, a14);
        __syncthreads();
        mm_wr<36, 36, 6, 216, 36, 6, 6, 1, SA>(lds, tid, a14);
    }
    __syncthreads();

    // ---- epilogue: out[o] = sum_e E[e]*(a*w22_0[e,o]+b*w22_1[e,o]); normalize ----
    {
        const float a0 = cfa[0][10], b0 = cfb[0][10];
        const float a1 = cfa[1][10], b1 = cfb[1][10];
        const float* __restrict__ w0 = pw.w[10];
        const float* __restrict__ w1 = w0 + 12960;
        float p0[10], p1[10];
#pragma unroll
        for (int o = 0; o < 10; o++) { p0[o] = 0.f; p1[o] = 0.f; }
        for (int e = tid; e < 1296; e += NTHREADS) {
            const float E0 = lds[SA + e];
            const float E1 = lds[ARENA + SA + e];
            const float* __restrict__ q0 = w0 + e * 10;
            const float* __restrict__ q1 = w1 + e * 10;
#pragma unroll
            for (int o = 0; o < 10; o++) {
                const float v0 = q0[o], v1 = q1[o];
                p0[o] += E0 * (a0 * v0 + b0 * v1);
                p1[o] += E1 * (a1 * v0 + b1 * v1);
            }
        }
#pragma unroll
        for (int o = 0; o < 10; o++)
            for (int off = 32; off > 0; off >>= 1) {
                p0[o] += __shfl_down(p0[o], off, 64);
                p1[o] += __shfl_down(p1[o], off, 64);
            }
        const int lane = tid & 63, wv = tid >> 6;
        if (lane == 0) {
#pragma unroll
            for (int o = 0; o < 10; o++) { red[wv][0][o] = p0[o]; red[wv][1][o] = p1[o]; }
        }
        __syncthreads();
        if (tid < 2) {
            float r[10];
            float ss = 0.f;
#pragma unroll
            for (int o = 0; o < 10; o++) {
                r[o] = red[0][tid][o] + red[1][tid][o] + red[2][tid][o] + red[3][tid][o];
                ss += r[o] * r[o];
            }
            const float inv = 1.f / sqrtf(ss);
#pragma unroll
            for (int o = 0; o < 10; o++) out[(s0 + tid) * 10 + o] = r[o] * inv;
        }
    }
#undef CF
}

extern "C" void kernel_launch(void* const* d_in, const int* in_sizes, int n_in,
                              void* d_out, int out_size, void* d_ws, size_t ws_size,
                              hipStream_t stream) {
    PW pw;
    for (int k = 0; k < 16; k++) {
        pw.w[k] = (const float*)d_in[1 + k];
        pw.perp[k] = in_sizes[1 + k] / 2;
    }
    float* gram = (float*)d_ws;             // 16*12 floats (4 partial slices/node)
    gram64<<<64, NTHREADS, 0, stream>>>(pw, gram);

    const float* x = (const float*)d_in[0];
    const int B = out_size / 10;            // 2048 samples
    peps_main<<<B / 2, NTHREADS, 0, stream>>>(x, pw, gram, (float*)d_out);
}

// Round 7
// 134.295 us; speedup vs baseline: 1.2727x; 1.0594x over previous
//
#include <hip/hip_runtime.h>
#include <math.h>

#define NTHREADS 256

// 16 node weight pointers.
struct PW {
    const float* w[16];
    int perp[16];
};

// ---------------------------------------------------------------------------
// Gram precompute, 4 partial slices per node (64 blocks), float4 loads.
// g[n*12 + slice*3 + {0,1,2}] = partial {<w0,w0>, <w0,w1>, <w1,w1>}.
// All per-plane sizes (36,216,1296,12960) are multiples of 4.
// ---------------------------------------------------------------------------
__global__ __launch_bounds__(NTHREADS) void gram64(PW pw, float* __restrict__ g) {
    const int n = blockIdx.x >> 2, sl = blockIdx.x & 3;
    const float* __restrict__ W = pw.w[n];
    const int m = pw.perp[n];
    float s00 = 0.f, s01 = 0.f, s11 = 0.f;
    for (int e = (sl * NTHREADS + threadIdx.x) * 4; e < m; e += NTHREADS * 16) {
        const float4 a = *reinterpret_cast<const float4*>(W + e);
        const float4 b = *reinterpret_cast<const float4*>(W + m + e);
        s00 += a.x * a.x + a.y * a.y + a.z * a.z + a.w * a.w;
        s01 += a.x * b.x + a.y * b.y + a.z * b.z + a.w * b.w;
        s11 += b.x * b.x + b.y * b.y + b.z * b.z + b.w * b.w;
    }
    for (int off = 32; off > 0; off >>= 1) {
        s00 += __shfl_down(s00, off, 64);
        s01 += __shfl_down(s01, off, 64);
        s11 += __shfl_down(s11, off, 64);
    }
    __shared__ float red[4][3];
    const int lane = threadIdx.x & 63, wv = threadIdx.x >> 6;
    if (lane == 0) { red[wv][0] = s00; red[wv][1] = s01; red[wv][2] = s11; }
    __syncthreads();
    if (threadIdx.x == 0) {
        float t0 = 0.f, t1 = 0.f, t2 = 0.f;
        for (int i = 0; i < 4; i++) { t0 += red[i][0]; t1 += red[i][1]; t2 += red[i][2]; }
        g[n * 12 + sl * 3 + 0] = t0; g[n * 12 + sl * 3 + 1] = t1; g[n * 12 + sl * 3 + 2] = t2;
    }
}

// ---------------------------------------------------------------------------
// LDS arena per sample (floats). 2 samples/block. 3 big slots + 5 small slots.
// Liveness audited in R2 (unchanged):
//  A: t11(P0-P3) TL(P3-P6) TOP(P6-P9) M1(P9-P10) E(P10-epi)
//  B: TL2(P2-P3) TR2(P4-P5) TR'(P5-P6) BL2(P7-P8) R'(P8-P10)
//  C: t12(P2-P5) t21(P6-P8) BL(P8-P9)
//  P: TL1(P1-P2) TR1(P3-P4) BL1(P5-P7)
//  Q: t00(P0-P1)@+0 t03(P1-P3)@+36 t30(P2-P5)@+72 t33(P5-P7)@+108 R1(P7-P8)full
//  X: t01(P0-P1) t13(P2-P4) t23(P5-P7)
//  Y: t10(P0-P2) t20(P3-P5) t32(P6-P8)
//  Z: t02(P1-P3) t31(P4-P7)
// All slot bases are multiples of 4 floats (16B) for b128 access.
// ---------------------------------------------------------------------------
constexpr int SA = 0, SB = 1296, SC = 2592;
constexpr int SP = 3888, SQ = 4104, SX = 4320, SY = 4536, SZ = 4752;
constexpr int ARENA = 4968;   // 2*ARENA*4 = 39744 B (+static 576 B) -> 4 blocks/CU

// ---------------------------------------------------------------------------
// Staging: t = al*w0 + be*w1, identity layout, float4 (all TOTs % 4 == 0,
// all DSTs % 4 == 0).
// ---------------------------------------------------------------------------
template<int TOT, int DST>
__device__ __forceinline__ void stg_id(float* __restrict__ lds, const float* __restrict__ W,
                                       float a0, float b0, float a1, float b1, int tid) {
    constexpr int QUADS = TOT / 4;
    for (int e = tid; e < 2 * QUADS; e += NTHREADS) {
        const int s = (e >= QUADS);
        const int p = e - s * QUADS;
        const float al = s ? a1 : a0, be = s ? b1 : b0;
        const float4 u0 = *reinterpret_cast<const float4*>(W + 4 * p);
        const float4 u1 = *reinterpret_cast<const float4*>(W + TOT + 4 * p);
        float4 rv;
        rv.x = al * u0.x + be * u1.x; rv.y = al * u0.y + be * u1.y;
        rv.z = al * u0.z + be * u1.z; rv.w = al * u0.w + be * u1.w;
        *reinterpret_cast<float4*>(lds + s * ARENA + DST + 4 * p) = rv;
    }
}

// Staging with permutation: dest dims (D0 outer .. D3 inner), src strides S0..S3.
template<int D0, int D1, int D2, int D3, int S0, int S1, int S2, int S3, int DST>
__device__ __forceinline__ void stg_pm(float* __restrict__ lds, const float* __restrict__ W,
                                       float a0, float b0, float a1, float b1, int tid) {
    constexpr int TOT = D0 * D1 * D2 * D3;
    for (int e = tid; e < 2 * TOT; e += NTHREADS) {
        const int s = (e >= TOT);
        const int d = e - s * TOT;
        int r = d;
        const int i3 = r % D3; r /= D3;
        const int i2 = r % D2; r /= D2;
        const int i1 = r % D1;
        const int i0 = r / D1;
        const int src = i0 * S0 + i1 * S1 + i2 * S2 + i3 * S3;
        const float al = s ? a1 : a0, be = s ? b1 : b0;
        lds[s * ARENA + DST + d] = al * W[src] + be * W[TOT + src];
    }
}

// ---------------------------------------------------------------------------
// Matmul: out[m,n] = sum_k A[k][m] * B[k][n]; A [K][M] m-contig, B [K][N]
// n-contig. Tile TM x TN per thread; TM/TN in {2,4} -> float2/float4 LDS reads
// (b64/b128). 4x4 on the 36x36 steps: 162 active threads, 2 LDS reads per
// 16 FMAs. acc/wr split so big steps can write IN-PLACE after a barrier.
// ---------------------------------------------------------------------------
template<int M, int N, int K, int TM, int TN, int AOFF, int BOFF>
__device__ __forceinline__ void mm_acc(const float* __restrict__ lds, int tid,
                                       float (&acc)[TM][TN]) {
    constexpr int WM = M / TM, WN = N / TN, PER_S = WM * WN, TOT = 2 * PER_S;
    static_assert(TOT <= NTHREADS, "tile overflow");
    static_assert(M % TM == 0 && N % TN == 0, "tile divide");
    if (tid >= TOT) return;
    const int s = (tid >= PER_S);
    const int r = tid - s * PER_S;
    const int mt = r / WN, nt = r - mt * WN;
    const float* __restrict__ Ab = lds + s * ARENA + AOFF + mt * TM;
    const float* __restrict__ Bb = lds + s * ARENA + BOFF + nt * TN;
#pragma unroll
    for (int i = 0; i < TM; i++)
#pragma unroll
        for (int j = 0; j < TN; j++) acc[i][j] = 0.f;
#pragma unroll 6
    for (int k = 0; k < K; ++k) {
        float a[TM], b[TN];
        if constexpr (TM == 4) {
            const float4 v = *reinterpret_cast<const float4*>(Ab + k * M);
            a[0] = v.x; a[1] = v.y; a[2] = v.z; a[3] = v.w;
        } else {
            const float2 v = *reinterpret_cast<const float2*>(Ab + k * M);
            a[0] = v.x; a[1] = v.y;
        }
        if constexpr (TN == 4) {
            const float4 v = *reinterpret_cast<const float4*>(Bb + k * N);
            b[0] = v.x; b[1] = v.y; b[2] = v.z; b[3] = v.w;
        } else {
            const float2 v = *reinterpret_cast<const float2*>(Bb + k * N);
            b[0] = v.x; b[1] = v.y;
        }
#pragma unroll
        for (int i = 0; i < TM; i++)
#pragma unroll
            for (int j = 0; j < TN; j++) acc[i][j] += a[i] * b[j];
    }
}

// Write with per-axis strides: m = m1*NM2+m2, n = n1*NN2+n2,
// addr = m1*OSM1 + m2*OSM2 + n1*OSN1 + n2*OSN2. float4 fast path when the
// written run is contiguous in n (NCONT) or m (MCONT).
template<int M, int N, int TM, int TN,
         int NM2, int OSM1, int OSM2, int NN2, int OSN1, int OSN2, int OOFF>
__device__ __forceinline__ void mm_wr(float* __restrict__ lds, int tid,
                                      const float (&acc)[TM][TN]) {
    constexpr int WM = M / TM, WN = N / TN, PER_S = WM * WN, TOT = 2 * PER_S;
    if (tid >= TOT) return;
    const int s = (tid >= PER_S);
    const int r = tid - s * PER_S;
    const int mt = r / WN, nt = r - mt * WN;
    float* __restrict__ Ob = lds + s * ARENA + OOFF;
    constexpr bool NCONT = (TN == 4) && (OSN2 == 1) && ((NN2 >= N) || (OSN1 == NN2));
    constexpr bool MCONT = (TM == 4) && (OSM2 == 1) && ((NM2 >= M) || (OSM1 == NM2));
    if constexpr (NCONT) {
        const int nb = nt * TN;
#pragma unroll
        for (int i = 0; i < TM; i++) {
            const int m = mt * TM + i;
            int m1, m2;
            if constexpr (NM2 >= M) { m1 = 0; m2 = m; }
            else                    { m1 = m / NM2; m2 = m - m1 * NM2; }
            float4 v; v.x = acc[i][0]; v.y = acc[i][1]; v.z = acc[i][2]; v.w = acc[i][3];
            *reinterpret_cast<float4*>(Ob + m1 * OSM1 + m2 * OSM2 + nb) = v;
        }
    } else if constexpr (MCONT) {
        const int mb = mt * TM;
#pragma unroll
        for (int j = 0; j < TN; j++) {
            const int n = nt * TN + j;
            int n1, n2;
            if constexpr (NN2 >= N) { n1 = 0; n2 = n; }
            else                    { n1 = n / NN2; n2 = n - n1 * NN2; }
            float4 v; v.x = acc[0][j]; v.y = acc[1][j]; v.z = acc[2][j]; v.w = acc[3][j];
            *reinterpret_cast<float4*>(Ob + n1 * OSN1 + n2 * OSN2 + mb) = v;
        }
    } else {
#pragma unroll
        for (int i = 0; i < TM; i++) {
            const int m = mt * TM + i;
            int m1, m2;
            if constexpr (NM2 >= M) { m1 = 0; m2 = m; }
            else                    { m1 = m / NM2; m2 = m - m1 * NM2; }
#pragma unroll
            for (int j = 0; j < TN; j++) {
                const int n = nt * TN + j;
                int n1, n2;
                if constexpr (NN2 >= N) { n1 = 0; n2 = n; }
                else                    { n1 = n / NN2; n2 = n - n1 * NN2; }
                Ob[m1 * OSM1 + m2 * OSM2 + n1 * OSN1 + n2 * OSN2] = acc[i][j];
            }
        }
    }
}

// Direct (non-deferred) matmul: output slot disjoint from all same-phase-live.
template<int M, int N, int K, int TM, int TN,
         int NM2, int OSM1, int OSM2, int NN2, int OSN1, int OSN2,
         int AOFF, int BOFF, int OOFF>
__device__ __forceinline__ void mmd(float* __restrict__ lds, int tid) {
    float acc[TM][TN];
    mm_acc<M, N, K, TM, TN, AOFF, BOFF>(lds, tid, acc);
    mm_wr<M, N, TM, TN, NM2, OSM1, OSM2, NN2, OSN1, OSN2, OOFF>(lds, tid, acc);
}

// ---------------------------------------------------------------------------
// Main: one block = 2 samples, 4 blocks/CU resident. Layout strides are
// byte-identical to the R1/R2-verified kernel; only tile shape (4x4) and
// vector widths changed.
// ---------------------------------------------------------------------------
__global__ __launch_bounds__(NTHREADS, 4) void peps_main(const float* __restrict__ x, PW pw,
                                                         const float* __restrict__ gram,
                                                         float* __restrict__ out) {
    __shared__ float lds[2 * ARENA];
    __shared__ float cfa[2][16], cfb[2][16];
    __shared__ float red[4][2][10];

    const int tid = threadIdx.x;
    const int s0 = blockIdx.x * 2;

    // per-node normalized coefficients for both samples (sum 4 gram partials)
    if (tid < 32) {
        const int sl = tid >> 4, n = tid & 15;
        const float a = x[(s0 + sl) * 32 + n * 2 + 0];
        const float b = x[(s0 + sl) * 32 + n * 2 + 1];
        float g0 = 0.f, g1 = 0.f, g2 = 0.f;
#pragma unroll
        for (int q = 0; q < 4; q++) {
            g0 += gram[n * 12 + q * 3 + 0];
            g1 += gram[n * 12 + q * 3 + 1];
            g2 += gram[n * 12 + q * 3 + 2];
        }
        const float inv = 1.f / sqrtf(a * a * g0 + 2.f * a * b * g1 + b * b * g2);
        cfa[sl][n] = a * inv; cfb[sl][n] = b * inv;
    }
    __syncthreads();

#define CF(WI) cfa[0][WI], cfb[0][WI], cfa[1][WI], cfb[1][WI]

    // P0: stage t00->Q0 [h00][v00], t01->X, t10->Y, t11->A
    stg_pm<1, 1, 6, 6, 0, 0, 1, 6, SQ + 0>(lds, pw.w[0], CF(0), tid);
    stg_id<216, SX>(lds, pw.w[1], CF(1), tid);
    stg_id<216, SY>(lds, pw.w[4], CF(4), tid);
    stg_id<1296, SA>(lds, pw.w[5], CF(5), tid);
    __syncthreads();

    // P1: S1 TL1[v00][(v01,h01)] = t00(Q0) x t01(X) -> P ; stage t02->Z, t03->Q1
    mmd<6, 36, 6, 2, 4, 6, 0, 36, 36, 0, 1, SQ + 0, SX, SP>(lds, tid);
    stg_pm<1, 6, 6, 6, 0, 1, 36, 6, SZ>(lds, pw.w[2], CF(2), tid);
    stg_id<36, SQ + 36>(lds, pw.w[3], CF(3), tid);
    __syncthreads();

    // P2: S2 TL2[v01][h10][h01][v10] = TL1(P) x t10(Y) -> B
    //     stage t13->X, t12->C [v02][h12][h11][v12], t30->Q2
    mmd<36, 36, 6, 4, 4, 6, 216, 6, 6, 1, 36, SP, SY, SB>(lds, tid);
    stg_id<216, SX>(lds, pw.w[7], CF(7), tid);
    stg_pm<6, 6, 6, 6, 216, 1, 36, 6, SC>(lds, pw.w[6], CF(6), tid);
    stg_id<36, SQ + 72>(lds, pw.w[12], CF(12), tid);
    __syncthreads();

    // P3: S3 TL = TL2(B) x t11(A) [K=36] (defer -> A)
    //     S4 TR1[v03][(h01,v02)] = t02(Z) x t03(Q1) -> P ; stage t20->Y
    {
        float a3[4][4];
        mm_acc<36, 36, 36, 4, 4, SB, SA>(lds, tid, a3);
        mmd<36, 6, 6, 4, 2, 36, 0, 1, 6, 0, 36, SZ, SQ + 36, SP>(lds, tid);
        stg_pm<1, 6, 6, 6, 0, 6, 36, 1, SY>(lds, pw.w[8], CF(8), tid);
        __syncthreads();
        mm_wr<36, 36, 4, 4, 6, 216, 6, 6, 1, 36, SA>(lds, tid, a3);  // TL [h01][h11][v10][v11]
    }
    __syncthreads();

    // P4: S5 TR2[v02][h12][h01][v13] = TR1(P) x t13(X) -> B ; stage t31->Z
    mmd<36, 36, 6, 4, 4, 6, 6, 216, 6, 36, 1, SP, SX, SB>(lds, tid);
    stg_pm<1, 6, 6, 6, 0, 6, 36, 1, SZ>(lds, pw.w[13], CF(13), tid);
    __syncthreads();

    // P5: S6 TR' = t12(C) x TR2(B) [K=36] (defer -> B)
    //     S8 BL1[h30][(v10,h20)] = t30(Q2) x t20(Y) -> P ; stage t33->Q3, t23->X
    {
        float a6[4][4];
        mm_acc<36, 36, 36, 4, 4, SC, SB>(lds, tid, a6);
        mmd<6, 36, 6, 2, 4, 6, 0, 36, 36, 0, 1, SQ + 72, SY, SP>(lds, tid);
        stg_id<36, SQ + 108>(lds, pw.w[15], CF(15), tid);
        stg_pm<1, 6, 6, 6, 0, 1, 36, 6, SX>(lds, pw.w[11], CF(11), tid);
        __syncthreads();
        mm_wr<36, 36, 4, 4, 6, 36, 6, 6, 216, 1, SB>(lds, tid, a6);  // TR' [h01][h11][v12][v13]
    }
    __syncthreads();

    // P6: S7 TOP = TL(A) x TR'(B) [K=36] (defer -> A)
    //     stage t21->C [h20][v21][v11][h21], t32->Y
    {
        float a7[4][4];
        mm_acc<36, 36, 36, 4, 4, SA, SB>(lds, tid, a7);
        stg_pm<6, 6, 6, 6, 36, 6, 216, 1, SC>(lds, pw.w[9], CF(9), tid);
        stg_pm<1, 6, 6, 6, 0, 1, 36, 6, SY>(lds, pw.w[14], CF(14), tid);
        __syncthreads();
        mm_wr<36, 36, 4, 4, 6, 216, 36, 6, 6, 1, SA>(lds, tid, a7); // TOP [v10][v11][v12][v13]
    }
    __syncthreads();

    // P7: S9 BL2[h20][v21][v10][h31] = BL1(P) x t31(Z) -> B
    //     S12 R1[h32][(v13,h22)] = t23(X) x t33(Q3) (defer -> Q full)
    {
        float a12[4][2];
        mm_acc<36, 6, 6, 4, 2, SX, SQ + 108>(lds, tid, a12);
        mmd<36, 36, 6, 4, 4, 6, 6, 216, 6, 36, 1, SP, SZ, SB>(lds, tid);
        __syncthreads();
        mm_wr<36, 6, 4, 2, 36, 0, 1, 6, 0, 36, SQ>(lds, tid, a12);
    }
    __syncthreads();

    // P8: S10 BL = BL2(B) x t21(C) [K=36] (defer -> C)
    //     S13 R' = R1(Q) x t32(Y) [K=6]  (defer -> B)
    {
        float a10[4][4], a13[4][4];
        mm_acc<36, 36, 36, 4, 4, SB, SC>(lds, tid, a10);
        mm_acc<36, 36, 6, 4, 4, SQ, SY>(lds, tid, a13);
        __syncthreads();
        mm_wr<36, 36, 4, 4, 6, 216, 6, 6, 36, 1, SC>(lds, tid, a10); // BL [v10][v11][h31][h21]
        mm_wr<36, 36, 4, 4, 6, 216, 1, 6, 6, 36, SB>(lds, tid, a13); // R' [v13][h31][v22][h22]
    }
    __syncthreads();

    // P9: S11 M1 = TOP(A) x BL(C) [K=36] (defer -> A)
    {
        float a11[4][4];
        mm_acc<36, 36, 36, 4, 4, SA, SC>(lds, tid, a11);
        __syncthreads();
        mm_wr<36, 36, 4, 4, 6, 6, 216, 6, 36, 1, SA>(lds, tid, a11); // M1 [v13][h31][v12][h21]
    }
    __syncthreads();

    // P10: S14 E = M1(A) x R'(B) [K=36] (defer -> A) ; E [v12][h21][v22][h22]
    {
        float a14[4][4];
        mm_acc<36, 36, 36, 4, 4, SA, SB>(lds, tid, a14);
        __syncthreads();
        mm_wr<36, 36, 4, 4, 6, 216, 36, 6, 6, 1, SA>(lds, tid, a14);
    }
    __syncthreads();

    // ---- epilogue: out[o] = sum_e E[e]*(a*w22_0[e,o]+b*w22_1[e,o]); normalize ----
    {
        const float a0 = cfa[0][10], b0 = cfb[0][10];
        const float a1 = cfa[1][10], b1 = cfb[1][10];
        const float* __restrict__ w0 = pw.w[10];
        const float* __restrict__ w1 = w0 + 12960;
        float p0[10], p1[10];
#pragma unroll
        for (int o = 0; o < 10; o++) { p0[o] = 0.f; p1[o] = 0.f; }
        for (int f = tid; f < 324; f += NTHREADS) {
            const float4 E0 = *reinterpret_cast<const float4*>(lds + SA + 4 * f);
            const float4 E1 = *reinterpret_cast<const float4*>(lds + ARENA + SA + 4 * f);
            const float e0[4] = {E0.x, E0.y, E0.z, E0.w};
            const float e1[4] = {E1.x, E1.y, E1.z, E1.w};
#pragma unroll
            for (int u = 0; u < 4; u++) {
                const int e = 4 * f + u;
                const float* __restrict__ q0 = w0 + e * 10;
                const float* __restrict__ q1 = w1 + e * 10;
#pragma unroll
                for (int o = 0; o < 10; o++) {
                    const float v0 = q0[o], v1 = q1[o];
                    p0[o] += e0[u] * (a0 * v0 + b0 * v1);
                    p1[o] += e1[u] * (a1 * v0 + b1 * v1);
                }
            }
        }
#pragma unroll
        for (int o = 0; o < 10; o++)
            for (int off = 32; off > 0; off >>= 1) {
                p0[o] += __shfl_down(p0[o], off, 64);
                p1[o] += __shfl_down(p1[o], off, 64);
            }
        const int lane = tid & 63, wv = tid >> 6;
        if (lane == 0) {
#pragma unroll
            for (int o = 0; o < 10; o++) { red[wv][0][o] = p0[o]; red[wv][1][o] = p1[o]; }
        }
        __syncthreads();
        if (tid < 2) {
            float r[10];
            float ss = 0.f;
#pragma unroll
            for (int o = 0; o < 10; o++) {
                r[o] = red[0][tid][o] + red[1][tid][o] + red[2][tid][o] + red[3][tid][o];
                ss += r[o] * r[o];
            }
            const float inv = 1.f / sqrtf(ss);
#pragma unroll
            for (int o = 0; o < 10; o++) out[(s0 + tid) * 10 + o] = r[o] * inv;
        }
    }
#undef CF
}

extern "C" void kernel_launch(void* const* d_in, const int* in_sizes, int n_in,
                              void* d_out, int out_size, void* d_ws, size_t ws_size,
                              hipStream_t stream) {
    PW pw;
    for (int k = 0; k < 16; k++) {
        pw.w[k] = (const float*)d_in[1 + k];
        pw.perp[k] = in_sizes[1 + k] / 2;
    }
    float* gram = (float*)d_ws;             // 16*12 floats (4 partial slices/node)
    gram64<<<64, NTHREADS, 0, stream>>>(pw, gram);

    const float* x = (const float*)d_in[0];
    const int B = out_size / 10;            // 2048 samples
    peps_main<<<B / 2, NTHREADS, 0, stream>>>(x, pw, gram, (float*)d_out);
}